// Round 4
// baseline (186.503 us; speedup 1.0000x reference)
//
#include <hip/hip_runtime.h>
#include <hip/hip_bf16.h>
#include <math.h>

#define NCLS 256
#define PER_CLASS 128
#define NSUP 5
#define NQRY 123              // PER_CLASS - NSUP
#define NVIEW 2
#define DD 384
#define NQ_TOT (NCLS * NQRY)  // 31488
#define BM 128                // queries per block
#define BK 32                 // k-tile (elems)
#define NKT (DD / BK)         // 12
#define NPROTO (NVIEW * NCLS)           // 512 proto blocks
#define QCONV_BLOCKS 1536
#define CHUNKS (NVIEW * NQ_TOT * (DD / 8))  // 3,022,848 8-elem chunks

typedef __attribute__((ext_vector_type(8))) short short8;
typedef __attribute__((ext_vector_type(4))) float floatx4;

union FragU { uint4 u; short8 s; };
union PkU { __hip_bfloat162 b2; unsigned int u; };

__device__ __forceinline__ unsigned int cvt2bf(float lo, float hi) {
    PkU p;
    p.b2 = __float22bfloat162_rn(make_float2(lo, hi));
    return p.u;
}

// async global->LDS, 16B per lane; LDS dest is wave-uniform base + lane*16 (HW rule)
__device__ __forceinline__ void gll16(const ushort* g, ushort* l) {
    __builtin_amdgcn_global_load_lds(
        (const __attribute__((address_space(1))) unsigned int*)g,
        (__attribute__((address_space(3))) unsigned int*)l, 16, 0, 0);
}

// barrier WITHOUT the vmcnt(0) drain __syncthreads would emit.
#define BARRIER() asm volatile("s_waitcnt lgkmcnt(0)\n\ts_barrier" ::: "memory")
#define WAITVM(n) asm volatile("s_waitcnt vmcnt(" #n ")" ::: "memory")

// ---------- kernel 1: prototypes (bf16 + y2 + out-zero)  ||  query f32->bf16 conversion ----------
__global__ __launch_bounds__(384) void prep_kernel(const float* __restrict__ reps,
                                                   ushort* __restrict__ pbf,
                                                   float* __restrict__ y2,
                                                   ushort* __restrict__ qbf,
                                                   float* __restrict__ out) {
    __shared__ float wp[6];
    const int t = threadIdx.x;
    if (blockIdx.x < NPROTO) {
        // ---- proto role (verified r0-r3) ----
        const int b = blockIdx.x;          // v*256 + c
        const int c = b & 255, v = b >> 8;
        if (b == 0 && t == 0) out[0] = 0.f;
        const float* p = reps + ((size_t)(c * PER_CLASS) * NVIEW + v) * DD + t;
        float s = 0.f;
#pragma unroll
        for (int k = 0; k < NSUP; ++k) s += p[(size_t)k * NVIEW * DD];
        s *= 0.2f;
        __hip_bfloat16 h = __float2bfloat16(s);
        pbf[(size_t)b * DD + t] = *reinterpret_cast<ushort*>(&h);
        float q = s * s;
#pragma unroll
        for (int o = 1; o < 64; o <<= 1) q += __shfl_xor(q, o);
        if ((t & 63) == 0) wp[t >> 6] = q;
        __syncthreads();
        if (t == 0) y2[b] = wp[0] + wp[1] + wp[2] + wp[3] + wp[4] + wp[5];
    } else {
        // ---- qconv role: queries f32 -> bf16, layout qbf[v][nq][384] ----
        // chunk g: row = v*NQ_TOT+nq, d8 = elem-octet. Same RN conversion as the old
        // in-kernel cvt -> MFMA inputs bit-identical.
        const int g0 = (blockIdx.x - NPROTO) * 384 + t;
        for (int g = g0; g < CHUNKS; g += QCONV_BLOCKS * 384) {
            const int row = g / 48;
            const int d8 = g - row * 48;
            const int v = row / NQ_TOT;
            const int nq = row - v * NQ_TOT;
            const int c = nq / NQRY;
            const int qi = nq - c * NQRY;
            const float* src = reps +
                (size_t)((c * PER_CLASS + NSUP + qi) * NVIEW + v) * DD + d8 * 8;
            const float4 a = *(const float4*)src;
            const float4 b4 = *(const float4*)(src + 4);
            uint4 w;
            w.x = cvt2bf(a.x, a.y);  w.y = cvt2bf(a.z, a.w);
            w.z = cvt2bf(b4.x, b4.y); w.w = cvt2bf(b4.z, b4.w);
            *(uint4*)(qbf + (size_t)row * DD + d8 * 8) = w;
        }
    }
}

// ---------- kernel 2: all-gll bf16 MFMA GEMM + fused logsumexp/NLL ----------
// Both operands arrive via global_load_lds (no register staging, no cvt, no ds_writes).
// 3-deep buffers, 2-iteration flight window, counted vmcnt(3), ONE barrier per tile.
// LDS rows are 64B (32 bf16): frag read slot = quad + 4*(col&1) -> provably uniform
// bank distribution, no swizzle needed on either side.
__global__ __launch_bounds__(512, 4) void main_kernel(const ushort* __restrict__ qbf,
                                                      const ushort* __restrict__ pbf,
                                                      const float* __restrict__ y2g,
                                                      float* __restrict__ out) {
    __shared__ ushort q_lds[3][BM * 32];    // 3 x 8192 B
    __shared__ ushort p_lds[3][NCLS * 32];  // 3 x 16384 B   (epilogue overlays q_lds)

    const int t = threadIdx.x;
    const int v = blockIdx.y;
    const int q0 = blockIdx.x * BM;
    const int wave = t >> 6;
    const int lane = t & 63;
    const int col = lane & 15;   // MFMA m/n index
    const int quad = lane >> 4;  // MFMA k-chunk / C row group
    const int wm = wave >> 2;    // query half  (0..1)
    const int wn = wave & 3;     // class quarter (0..3)

    // gll maps: one instr = 16 rows x 64B; lane l -> row base+(l>>2), 16B chunk (l&3).
    // Q: wave w stages tile rows w*16..w*16+15 (identity map to queries q0+row).
    // P: wave w stages rows {w*16..+15} and {128+w*16..+15}.
    const ushort* qsrc = qbf + (size_t)(v * NQ_TOT + q0 + wave * 16 + (lane >> 2)) * DD
                             + (lane & 3) * 8;
    const ushort* psrc0 = pbf + (size_t)(v * NCLS + wave * 16 + (lane >> 2)) * DD
                              + (lane & 3) * 8;
    const ushort* psrc1 = psrc0 + (size_t)128 * DD;

    const int qdst = wave * 512;           // ushort offsets (wave-uniform)
    const int pdst1 = 4096 + wave * 512;

    floatx4 acc[4][4];
#pragma unroll
    for (int mt = 0; mt < 4; ++mt)
#pragma unroll
        for (int nt = 0; nt < 4; ++nt) acc[mt][nt] = (floatx4)0.f;

#define GLLT(kt, b)                                                                \
    do {                                                                           \
        gll16(qsrc + (kt) * BK, &q_lds[b][qdst]);                                  \
        gll16(psrc0 + (kt) * BK, &p_lds[b][qdst]);                                 \
        gll16(psrc1 + (kt) * BK, &p_lds[b][pdst1]);                                \
    } while (0)

#define COMPUTE(b)                                                                 \
    do {                                                                           \
        short8 af[4];                                                              \
        _Pragma("unroll") for (int mt = 0; mt < 4; ++mt) {                         \
            FragU f;                                                               \
            f.u = *(const uint4*)&q_lds[b][(wm * 64 + mt * 16 + col) * 32 + quad * 8]; \
            af[mt] = f.s;                                                          \
        }                                                                          \
        _Pragma("unroll") for (int nt = 0; nt < 4; ++nt) {                         \
            FragU bb;                                                              \
            bb.u = *(const uint4*)&p_lds[b][(wn * 64 + nt * 16 + col) * 32 + quad * 8]; \
            _Pragma("unroll") for (int mt = 0; mt < 4; ++mt)                       \
                acc[mt][nt] = __builtin_amdgcn_mfma_f32_16x16x32_bf16(af[mt], bb.s, acc[mt][nt], 0, 0, 0); \
        }                                                                          \
    } while (0)

    // ---- prologue: tiles 0,1,2 in flight (3 instrs each) ----
    GLLT(0, 0);
    GLLT(1, 1);
    GLLT(2, 2);
    WAITVM(6);          // tile 0 landed (own portion); tiles 1,2 stay in flight
    BARRIER();          // all portions of tile 0 visible

#pragma unroll
    for (int kt = 0; kt < NKT; ++kt) {
        COMPUTE(kt % 3);
        if (kt == NKT - 1) break;
        if (kt + 2 < NKT) { WAITVM(3); } else { WAITVM(0); }  // tile kt+1 landed; kt+2 flies
        BARRIER();                     // publish tile kt+1; all waves done with buf kt%3
        if (kt + 3 < NKT) GLLT(kt + 3, kt % 3);
    }

    // ---- epilogue (r3-verified structure; scratch overlays q_lds) ----
    __syncthreads();
    float* eplds = (float*)&q_lds[0][0];
    float (*pmx)[4] = (float(*)[4])eplds;            // 128 x 4
    float (*pse)[4] = (float(*)[4])(eplds + 512);    // 128 x 4
    float* wred = eplds + 1024;                      // 16

    float y2c[4];
#pragma unroll
    for (int nt = 0; nt < 4; ++nt) y2c[nt] = y2g[v * NCLS + wn * 64 + nt * 16 + col];

    float corr = 0.f;
#pragma unroll
    for (int mt = 0; mt < 4; ++mt) {
#pragma unroll
        for (int r = 0; r < 4; ++r) {
            const int qloc = wm * 64 + mt * 16 + quad * 4 + r;
            const int n = q0 + qloc;
            const int cn = n / NQRY;
            float s[4];
            float mx = -1e30f;
#pragma unroll
            for (int nt = 0; nt < 4; ++nt) {
                s[nt] = 2.f * acc[mt][nt][r] - y2c[nt];
                mx = fmaxf(mx, s[nt]);
                if (cn == wn * 64 + nt * 16 + col) corr += s[nt];
            }
#pragma unroll
            for (int o = 1; o < 16; o <<= 1) mx = fmaxf(mx, __shfl_xor(mx, o));
            float e = 0.f;
#pragma unroll
            for (int nt = 0; nt < 4; ++nt) e += __expf(s[nt] - mx);
#pragma unroll
            for (int o = 1; o < 16; o <<= 1) e += __shfl_xor(e, o);
            if (col == 0) { pmx[qloc][wn] = mx; pse[qloc][wn] = e; }
        }
    }
#pragma unroll
    for (int o = 1; o < 64; o <<= 1) corr += __shfl_xor(corr, o);
    if (lane == 0) wred[wave] = corr;
    __syncthreads();

    float lval = 0.f;
    if (t < BM) {
        float m0 = pmx[t][0], m1 = pmx[t][1], m2 = pmx[t][2], m3 = pmx[t][3];
        float M = fmaxf(fmaxf(m0, m1), fmaxf(m2, m3));
        float E = pse[t][0] * __expf(m0 - M) + pse[t][1] * __expf(m1 - M) +
                  pse[t][2] * __expf(m2 - M) + pse[t][3] * __expf(m3 - M);
        lval = M + __logf(E);
    }
#pragma unroll
    for (int o = 1; o < 64; o <<= 1) lval += __shfl_xor(lval, o);
    if (lane == 0) wred[8 + wave] = lval;
    __syncthreads();

    if (t == 0) {
        float tot = (wred[8] + wred[9] + wred[10] + wred[11] +
                     wred[12] + wred[13] + wred[14] + wred[15]) -
                    (wred[0] + wred[1] + wred[2] + wred[3] +
                     wred[4] + wred[5] + wred[6] + wred[7]);
        atomicAdd(out, tot * (1.f / (float)(NQ_TOT * NVIEW)));
    }
}

extern "C" void kernel_launch(void* const* d_in, const int* in_sizes, int n_in,
                              void* d_out, int out_size, void* d_ws, size_t ws_size,
                              hipStream_t stream) {
    const float* reps = (const float*)d_in[0];
    ushort* pbf = (ushort*)d_ws;                        // 393216 B
    float* y2 = (float*)(pbf + NVIEW * NCLS * DD);      // 2048 B
    ushort* qbf = (ushort*)(y2 + NVIEW * NCLS);         // 48.4 MB
    float* out = (float*)d_out;

    prep_kernel<<<dim3(NPROTO + QCONV_BLOCKS), dim3(384), 0, stream>>>(reps, pbf, y2, qbf, out);
    main_kernel<<<dim3(NQ_TOT / BM, NVIEW), dim3(512), 0, stream>>>(qbf, pbf, y2, out);
}